// Round 8
// baseline (282.700 us; speedup 1.0000x reference)
//
#include <hip/hip_runtime.h>

// ---------- types ----------
typedef __bf16 bf16x8 __attribute__((ext_vector_type(8)));
typedef float  f32x4  __attribute__((ext_vector_type(4)));

__device__ __forceinline__ unsigned short f2bf(float f) {
    union { float f; unsigned int u; } x; x.f = f;
    unsigned int r = (x.u + 0x7FFFu + ((x.u >> 16) & 1u)) >> 16;  // RNE
    return (unsigned short)r;
}

// async global->LDS, 16B per lane; LDS dst is wave-uniform base + lane*16
typedef const __attribute__((address_space(1))) unsigned short gu16;
typedef __attribute__((address_space(3)))       unsigned short lu16;
__device__ __forceinline__ void gl_lds16(const unsigned short* g, unsigned short* l) {
    __builtin_amdgcn_global_load_lds((gu16*)g, (lu16*)l, 16, 0, 0);
}

// ==========================================================================
// Double-buffered GEMM core (128x128 tile, BK=32, 4 waves 2x2, wave 64x64)
// ==========================================================================
__device__ __forceinline__ void stage_tiles(
    const unsigned short* __restrict__ Ab, int lda,
    const unsigned short* __restrict__ Bb, int ldb,
    int k0, unsigned short* Ad, unsigned short* Bd,
    int wave, int r0, int c0)
{
    gl_lds16(Ab + (long)r0 * lda + c0 + k0,        Ad + wave * 512);
    gl_lds16(Ab + (long)(r0 + 64) * lda + c0 + k0, Ad + 2048 + wave * 512);
    gl_lds16(Bb + (long)r0 * ldb + c0 + k0,        Bd + wave * 512);
    gl_lds16(Bb + (long)(r0 + 64) * ldb + c0 + k0, Bd + 2048 + wave * 512);
}

__device__ __forceinline__ void gemm_core_db(
    const unsigned short* __restrict__ Ab, int lda,
    const unsigned short* __restrict__ Bb, int ldb,
    int K, f32x4 (&acc)[4][4],
    unsigned short* As, unsigned short* Bs)
{
    const int tid  = threadIdx.x;
    const int lane = tid & 63;
    const int wave = tid >> 6;
    const int wm   = (wave >> 1) * 64;
    const int wn   = (wave & 1) * 64;
    const int l16  = lane & 15;
    const int quad = lane >> 4;

    const int r0 = wave * 16 + (lane >> 2);
    const int c0 = (lane & 3) * 8;

    stage_tiles(Ab, lda, Bb, ldb, 0, As, Bs, wave, r0, c0);

    int sel = 0;
    for (int k0 = 0; k0 < K; k0 += 32) {
        __syncthreads();
        if (k0 + 32 < K)
            stage_tiles(Ab, lda, Bb, ldb, k0 + 32,
                        As + (sel ^ 1) * 4096, Bs + (sel ^ 1) * 4096, wave, r0, c0);

        const unsigned short* Ap = As + sel * 4096;
        const unsigned short* Bp = Bs + sel * 4096;
        bf16x8 af[4], bfr[4];
        #pragma unroll
        for (int mi = 0; mi < 4; mi++)
            af[mi] = *(const bf16x8*)&Ap[(wm + mi * 16 + l16) * 32 + quad * 8];
        #pragma unroll
        for (int ni = 0; ni < 4; ni++)
            bfr[ni] = *(const bf16x8*)&Bp[(wn + ni * 16 + l16) * 32 + quad * 8];
        #pragma unroll
        for (int mi = 0; mi < 4; mi++)
            #pragma unroll
            for (int ni = 0; ni < 4; ni++)
                acc[mi][ni] = __builtin_amdgcn_mfma_f32_16x16x32_bf16(af[mi], bfr[ni], acc[mi][ni], 0, 0, 0);
        sel ^= 1;
    }
}

// ==========================================================================
// Generic GEMM kernel (qkv via qkv_k, proj): trans-out / bias / residual
// ==========================================================================
template<typename OutT, bool TRANS_OUT, bool HAS_BIAS, bool HAS_RESID>
__global__ __launch_bounds__(256) void gemm_k(
    const unsigned short* __restrict__ Ag, long sA, int lda,
    const unsigned short* __restrict__ Bg, long sB, int ldb,
    OutT* __restrict__ Cg, long sC, int ldc,
    const float* __restrict__ bias,
    const float* __restrict__ resid, long sR,
    float alpha, int K)
{
    __shared__ __align__(16) unsigned short As[2 * 4096];
    __shared__ __align__(16) unsigned short Bs[2 * 4096];

    const unsigned short* Ab = Ag + (long)blockIdx.z * sA + (long)(blockIdx.y * 128) * lda;
    const unsigned short* Bb = Bg + (long)blockIdx.z * sB + (long)(blockIdx.x * 128) * ldb;

    f32x4 acc[4][4] = {};
    gemm_core_db(Ab, lda, Bb, ldb, K, acc, As, Bs);

    const int lane = threadIdx.x & 63;
    const int wave = threadIdx.x >> 6;
    const int l16  = lane & 15;
    const int quad = lane >> 4;
    const int mb = blockIdx.y * 128 + (wave >> 1) * 64;
    const int nb = blockIdx.x * 128 + (wave & 1) * 64;

    #pragma unroll
    for (int mi = 0; mi < 4; mi++) {
        #pragma unroll
        for (int ni = 0; ni < 4; ni++) {
            f32x4 v = acc[mi][ni];
            const int m0 = mb + mi * 16 + quad * 4;
            const int n  = nb + ni * 16 + l16;
            float o[4];
            #pragma unroll
            for (int r = 0; r < 4; r++) {
                float val = v[r] * alpha;
                if (HAS_BIAS) val += bias[m0 + r];
                o[r] = val;
            }
            if constexpr (!TRANS_OUT) {
                const long base = (long)blockIdx.z * sC;
                #pragma unroll
                for (int r = 0; r < 4; r++) {
                    float val = o[r];
                    if (HAS_RESID) val += resid[(long)blockIdx.z * sR + (long)(m0 + r) * ldc + n];
                    long idx = base + (long)(m0 + r) * ldc + n;
                    if constexpr (sizeof(OutT) == 2) ((unsigned short*)Cg)[idx] = f2bf(val);
                    else                              ((float*)Cg)[idx] = val;
                }
            } else {
                const long idx = (long)blockIdx.z * sC + (long)n * ldc + m0;
                if constexpr (sizeof(OutT) == 2) {
                    ushort4 p; p.x = f2bf(o[0]); p.y = f2bf(o[1]); p.z = f2bf(o[2]); p.w = f2bf(o[3]);
                    *(ushort4*)((unsigned short*)Cg + idx) = p;
                } else {
                    float4 p; p.x = o[0]; p.y = o[1]; p.z = o[2]; p.w = o[3];
                    *(float4*)((float*)Cg + idx) = p;
                }
            }
        }
    }
}

// ==========================================================================
// Fused QKV GEMM: A = Wqkv [1536][512], B = xnT [n][c].
// y 0..3 -> qT (trans), 4..7 -> kT (trans), 8..11 -> vB (natural).
// ==========================================================================
__global__ __launch_bounds__(256) void qkv_k(
    const unsigned short* __restrict__ Wqkv,
    const unsigned short* __restrict__ xnT,
    unsigned short* __restrict__ qT,
    unsigned short* __restrict__ kT,
    unsigned short* __restrict__ vB,
    const float* __restrict__ bqkv)
{
    __shared__ __align__(16) unsigned short As[2 * 4096];
    __shared__ __align__(16) unsigned short Bs[2 * 4096];

    const unsigned short* Ab = Wqkv + (long)(blockIdx.y * 128) * 512;
    const unsigned short* Bb = xnT + (long)blockIdx.z * 524288 + (long)(blockIdx.x * 128) * 512;

    f32x4 acc[4][4] = {};
    gemm_core_db(Ab, 512, Bb, 512, 512, acc, As, Bs);

    const int lane = threadIdx.x & 63;
    const int wave = threadIdx.x >> 6;
    const int l16  = lane & 15;
    const int quad = lane >> 4;
    const int mb = blockIdx.y * 128 + (wave >> 1) * 64;
    const int nb = blockIdx.x * 128 + (wave & 1) * 64;

    const int mat = blockIdx.y >> 2;
    const long zb = (long)blockIdx.z * 524288;

    #pragma unroll
    for (int mi = 0; mi < 4; mi++) {
        #pragma unroll
        for (int ni = 0; ni < 4; ni++) {
            f32x4 v = acc[mi][ni];
            const int m0 = mb + mi * 16 + quad * 4;
            const int n  = nb + ni * 16 + l16;
            float o[4];
            #pragma unroll
            for (int r = 0; r < 4; r++) o[r] = v[r] + bqkv[m0 + r];
            const int ml = m0 & 511;
            if (mat == 2) {
                #pragma unroll
                for (int r = 0; r < 4; r++)
                    vB[zb + (long)(ml + r) * 1024 + n] = f2bf(o[r]);
            } else {
                unsigned short* dst = (mat == 0) ? qT : kT;
                ushort4 p; p.x = f2bf(o[0]); p.y = f2bf(o[1]); p.z = f2bf(o[2]); p.w = f2bf(o[3]);
                *(ushort4*)(dst + zb + (long)n * 512 + ml) = p;
            }
        }
    }
}

// ==========================================================================
// Fused attention: P = exp(Q·K^T/sqrt(512)) and O = P·V with P resident in
// LDS (no-max exp, exact running row sums — validated R7). Per block:
// 32 Q-rows; 8 j-tiles of 128. Q in LDS 32x32 panels (conflict-free);
// K staged BK=64 via global_load_lds; V prefetched to registers at S-phase
// start (~2000cyc hiding); O in regs; epilogue scales 1/l -> OT[i][c].
// Grid (32, 16) = 512 blocks, 2 blocks/CU.
// ==========================================================================
__global__ __launch_bounds__(256, 2) void attn_k(
    const unsigned short* __restrict__ qT,
    const unsigned short* __restrict__ kT,
    const unsigned short* __restrict__ vB,
    unsigned short* __restrict__ OT)
{
    __shared__ __align__(16) unsigned short Qs[16 * 1024];  // 32 KB: 16 panels [32i][32c]
    __shared__ __align__(16) unsigned short Ks[2 * 4096];   // 16 KB: [128j][64c] as 2 sub-panels
    __shared__ __align__(16) unsigned short Ps[32 * 136];   // 8.5 KB, pad 136
    __shared__ float redS[4][32];

    const int b   = blockIdx.y;
    const int i0  = blockIdx.x * 32;
    const int tid = threadIdx.x;
    const int w    = tid >> 6;
    const int lane = tid & 63;
    const int l16  = lane & 15;
    const int quad = lane >> 4;
    const long zb  = (long)b * 524288;

    // ---- stage Q once: qT[i0..i0+32][0..512] -> 16 panels [32i][32c] ----
    {
        const uint4* qg = (const uint4*)(qT + zb + (long)i0 * 512);
        #pragma unroll
        for (int it = 0; it < 8; it++) {
            const int f = it * 256 + tid;        // uint4 index, 2048 total
            const int i = f >> 6;
            const int c = (f & 63) * 8;
            uint4 v = qg[f];
            *(uint4*)&Qs[(c >> 5) * 1024 + i * 32 + (c & 31)] = v;
        }
    }

    const int krow = w * 16 + (lane >> 2);       // staging row within 64-chunk
    const int kcol = (lane & 3) * 8;
    const float scale = 0.044194173824159216f;   // 512^-0.5

    f32x4 oacc[8][2] = {};
    float psum[2] = {0.f, 0.f};

    __syncthreads();                              // Qs visible

    for (int jt = 0; jt < 8; jt++) {
        const int j0 = jt * 128;

        // ---- V prefetch for this tile's PV (A-op: m=c, k=j) ----
        bf16x8 vreg[4][8];
        #pragma unroll
        for (int kb = 0; kb < 4; kb++)
            #pragma unroll
            for (int mt = 0; mt < 8; mt++)
                vreg[kb][mt] = *(const bf16x8*)(vB + zb +
                    (long)(w * 128 + mt * 16 + l16) * 1024 + j0 + kb * 32 + quad * 8);

        // ---- S^T[128j][32i] over c=512, BK=64 (2 sub-panels of 32) ----
        f32x4 sacc[2][2] = {};
        for (int r8 = 0; r8 < 8; r8++) {
            __syncthreads();                      // Ks free (prev reads done)
            #pragma unroll
            for (int sub = 0; sub < 2; sub++)
                #pragma unroll
                for (int ch = 0; ch < 2; ch++)
                    gl_lds16(kT + zb + (long)(j0 + ch * 64 + krow) * 512 + r8 * 64 + sub * 32 + kcol,
                             Ks + sub * 4096 + ch * 2048 + w * 512);
            __syncthreads();                      // Ks arrived

            #pragma unroll
            for (int sub = 0; sub < 2; sub++) {
                bf16x8 kf[2], qf[2];
                #pragma unroll
                for (int mt = 0; mt < 2; mt++)
                    kf[mt] = *(const bf16x8*)&Ks[sub * 4096 + (w * 32 + mt * 16 + l16) * 32 + quad * 8];
                const int panel = r8 * 2 + sub;
                #pragma unroll
                for (int nt = 0; nt < 2; nt++)
                    qf[nt] = *(const bf16x8*)&Qs[panel * 1024 + (nt * 16 + l16) * 32 + quad * 8];
                #pragma unroll
                for (int mt = 0; mt < 2; mt++)
                    #pragma unroll
                    for (int nt = 0; nt < 2; nt++)
                        sacc[mt][nt] = __builtin_amdgcn_mfma_f32_16x16x32_bf16(kf[mt], qf[nt], sacc[mt][nt], 0, 0, 0);
            }
        }

        // ---- P = exp(S*scale) -> Ps[i][j-local] (pad 136), row-sum accum ----
        #pragma unroll
        for (int mt = 0; mt < 2; mt++)
            #pragma unroll
            for (int nt = 0; nt < 2; nt++) {
                f32x4 v = sacc[mt][nt];
                float e0 = __expf(v[0] * scale), e1 = __expf(v[1] * scale);
                float e2 = __expf(v[2] * scale), e3 = __expf(v[3] * scale);
                psum[nt] += (e0 + e1) + (e2 + e3);
                ushort4 p; p.x = f2bf(e0); p.y = f2bf(e1); p.z = f2bf(e2); p.w = f2bf(e3);
                *(ushort4*)&Ps[(nt * 16 + l16) * 136 + w * 32 + mt * 16 + quad * 4] = p;
            }
        __syncthreads();                          // Ps complete (all waves)

        // ---- O[c][i] += V·P, k=j over 128 (4 BK=32 iters, V in regs) ----
        #pragma unroll
        for (int kb = 0; kb < 4; kb++) {
            bf16x8 pf[2];
            #pragma unroll
            for (int nt = 0; nt < 2; nt++)
                pf[nt] = *(const bf16x8*)&Ps[(nt * 16 + l16) * 136 + kb * 32 + quad * 8];
            #pragma unroll
            for (int mt = 0; mt < 8; mt++)
                #pragma unroll
                for (int nt = 0; nt < 2; nt++)
                    oacc[mt][nt] = __builtin_amdgcn_mfma_f32_16x16x32_bf16(vreg[kb][mt], pf[nt], oacc[mt][nt], 0, 0, 0);
        }
        // next tile's round-0 barrier protects Ks; Ps rewritten only after
        // 16 more barriers -> no trailing barrier needed here
    }

    // ---- row sums: reduce over quad (shfl) then waves (LDS) ----
    #pragma unroll
    for (int nt = 0; nt < 2; nt++) {
        psum[nt] += __shfl_xor(psum[nt], 16);
        psum[nt] += __shfl_xor(psum[nt], 32);
    }
    __syncthreads();                              // PV reads of Ps done; reuse barrier for redS
    if (quad == 0) { redS[w][l16] = psum[0]; redS[w][16 + l16] = psum[1]; }
    __syncthreads();

    float invl[2];
    #pragma unroll
    for (int nt = 0; nt < 2; nt++) {
        const int ii = nt * 16 + l16;
        invl[nt] = 1.f / ((redS[0][ii] + redS[1][ii]) + (redS[2][ii] + redS[3][ii]));
    }

    // ---- epilogue: OT[i][c] = O[c][i] / l[i] ----
    #pragma unroll
    for (int mt = 0; mt < 8; mt++)
        #pragma unroll
        for (int nt = 0; nt < 2; nt++) {
            f32x4 v = oacc[mt][nt];
            const int i = i0 + nt * 16 + l16;
            const int c = w * 128 + mt * 16 + quad * 4;
            ushort4 p;
            p.x = f2bf(v[0] * invl[nt]); p.y = f2bf(v[1] * invl[nt]);
            p.z = f2bf(v[2] * invl[nt]); p.w = f2bf(v[3] * invl[nt]);
            *(ushort4*)(OT + zb + (long)i * 512 + c) = p;
        }
}

// ==========================================================================
// GroupNorm: x[b][c][n] (fp32) -> xnT[b][n][c] (bf16), 32 groups of 16 ch
// ==========================================================================
__global__ __launch_bounds__(256) void gn_k(
    const float* __restrict__ x, const float* __restrict__ gsc,
    const float* __restrict__ gbi, unsigned short* __restrict__ xnT)
{
    __shared__ __align__(16) unsigned short ln[16 * 1024];
    __shared__ float red[8];
    const int b = blockIdx.y, g = blockIdx.x;
    const int tid = threadIdx.x, lane = tid & 63, wv = tid >> 6;

    const float4* x4 = (const float4*)(x + ((long)b * 512 + g * 16) * 1024);
    float4 vals[16];
    float s = 0.f, ss = 0.f;
    #pragma unroll
    for (int i = 0; i < 16; i++) {
        float4 v = x4[tid + i * 256];
        vals[i] = v;
        s  += v.x + v.y + v.z + v.w;
        ss += v.x * v.x + v.y * v.y + v.z * v.z + v.w * v.w;
    }
    for (int o = 32; o; o >>= 1) { s += __shfl_down(s, o); ss += __shfl_down(ss, o); }
    if (lane == 0) { red[wv * 2] = s; red[wv * 2 + 1] = ss; }
    __syncthreads();
    const float S  = red[0] + red[2] + red[4] + red[6];
    const float SS = red[1] + red[3] + red[5] + red[7];
    const float mean = S * (1.f / 16384.f);
    const float var  = SS * (1.f / 16384.f) - mean * mean;
    const float inv  = rsqrtf(var + 1e-5f);

    #pragma unroll
    for (int i = 0; i < 16; i++) {
        const int idx = tid + i * 256;
        const int c   = idx >> 8;
        const float sc = gsc[g * 16 + c] * inv;
        const float bi = gbi[g * 16 + c] - mean * sc;
        float4 v = vals[i];
        ushort4 p;
        p.x = f2bf(v.x * sc + bi); p.y = f2bf(v.y * sc + bi);
        p.z = f2bf(v.z * sc + bi); p.w = f2bf(v.w * sc + bi);
        ((ushort4*)ln)[idx] = p;
    }
    __syncthreads();

    unsigned short* op = xnT + (long)b * 1024 * 512 + g * 16;
    for (int rep = 0; rep < 4; rep++) {
        const int n = rep * 256 + tid;
        union { unsigned short u[16]; uint4 v[2]; } t;
        #pragma unroll
        for (int c = 0; c < 16; c++) t.u[c] = ln[c * 1024 + n];
        *(uint4*)&op[(long)n * 512]     = t.v[0];
        *(uint4*)&op[(long)n * 512 + 8] = t.v[1];
    }
}

// ---------- weights fp32 -> bf16 + bias concat (y==4 path) ----------
__global__ __launch_bounds__(256) void wconv_k(
    const float* __restrict__ w0, const float* __restrict__ w1,
    const float* __restrict__ w2, const float* __restrict__ w3,
    const float* __restrict__ b0, const float* __restrict__ b1,
    const float* __restrict__ b2,
    unsigned short* __restrict__ out, float* __restrict__ bqkv)
{
    const int m = blockIdx.y;
    const int i = blockIdx.x * 256 + threadIdx.x;
    if (m == 4) {
        if (i < 384) {
            const int which = i >> 7, off = i & 127;
            const float* src = (which == 0) ? b0 : (which == 1) ? b1 : b2;
            ((float4*)bqkv)[i] = ((const float4*)src)[off];
        }
        return;
    }
    const float* src = (m == 0) ? w0 : (m == 1) ? w1 : (m == 2) ? w2 : w3;
    float4 v = ((const float4*)src)[i];
    ushort4 o; o.x = f2bf(v.x); o.y = f2bf(v.y); o.z = f2bf(v.z); o.w = f2bf(v.w);
    ((ushort4*)(out + (long)m * 262144))[i] = o;
}

// ==========================================================================
extern "C" void kernel_launch(void* const* d_in, const int* in_sizes, int n_in,
                              void* d_out, int out_size, void* d_ws, size_t ws_size,
                              hipStream_t stream)
{
    const float* x   = (const float*)d_in[0];
    const float* gsc = (const float*)d_in[1];
    const float* gbi = (const float*)d_in[2];
    const float* wq  = (const float*)d_in[3];
    const float* bq  = (const float*)d_in[4];
    const float* wk  = (const float*)d_in[5];
    const float* bk  = (const float*)d_in[6];
    const float* wv  = (const float*)d_in[7];
    const float* bv  = (const float*)d_in[8];
    const float* wp  = (const float*)d_in[9];
    const float* bp  = (const float*)d_in[10];
    float* out = (float*)d_out;

    char* ws = (char*)d_ws;
    unsigned short* xnT = (unsigned short*)(ws);               // 16 MB [b][n][c]; reused as OT
    unsigned short* qT  = (unsigned short*)(ws + 16777216);    // 16 MB [b][i][c]
    unsigned short* kT  = (unsigned short*)(ws + 33554432);    // 16 MB [b][j][c]
    unsigned short* vB  = (unsigned short*)(ws + 50331648);    // 16 MB [b][c][j]
    unsigned short* Wb  = (unsigned short*)(ws + 100663296);   // 2 MB: wq|wk|wv|wp bf16
    float*          bqkv= (float*)        (ws + 102760448);    // 6 KB
    unsigned short* OT  = xnT;                                 // alias: xnT dead after QKV

    const long sBCN = 512L * 1024;

    wconv_k<<<dim3(256, 5), 256, 0, stream>>>(wq, wk, wv, wp, bq, bk, bv, Wb, bqkv);
    gn_k<<<dim3(32, 16), 256, 0, stream>>>(x, gsc, gbi, xnT);

    // fused QKV: qT[i][c], kT[j][c], vB[c][j]
    qkv_k<<<dim3(8, 12, 16), 256, 0, stream>>>(Wb, xnT, qT, kT, vB, bqkv);

    // fused attention: P in LDS, O -> OT[i][c]
    attn_k<<<dim3(32, 16), 256, 0, stream>>>(qT, kT, vB, OT);

    // out = Wp * O + bp + x
    gemm_k<float, false, true, true><<<dim3(8, 4, 16), 256, 0, stream>>>(
        Wb + 786432, 0, 512, OT, sBCN, 512, out, sBCN, 1024, bp, x, sBCN, 1.f, 512);
}